// Round 1
// baseline (895.456 us; speedup 1.0000x reference)
//
#include <hip/hip_runtime.h>
#include <hip/hip_bf16.h>

// Problem constants
#define B_ 32
#define T_ 64
#define E_ 512
#define H_ 512
#define V_ 10000
#define G4 2048   // 4*H

using bf16x8 = __attribute__((ext_vector_type(8))) short;  // 8 bf16 in 4 VGPRs
using f32x4  = __attribute__((ext_vector_type(4))) float;

__device__ inline f32x4 mfma16(bf16x8 a, bf16x8 b, f32x4 c) {
  return __builtin_amdgcn_mfma_f32_16x16x32_bf16(a, b, c, 0, 0, 0);
}

// fp32 -> bf16 round-to-nearest-even, stored as short
__device__ inline short f2bf(float x) {
  unsigned u = __builtin_bit_cast(unsigned, x);
  u = (u + 0x7fffu + ((u >> 16) & 1u)) >> 16;
  return (short)u;
}

__device__ inline float sigm(float x) { return 1.f / (1.f + expf(-x)); }

// ---------------- prep kernels ----------------

__global__ void cast_bf16_kernel(const float* __restrict__ in, short* __restrict__ out, int n) {
  int i = blockIdx.x * blockDim.x + threadIdx.x;
  int stride = gridDim.x * blockDim.x;
  for (; i < n; i += stride) out[i] = f2bf(in[i]);
}

__global__ void bsum_kernel(const float* __restrict__ bi, const float* __restrict__ bh,
                            float* __restrict__ bs) {
  int i = blockIdx.x * blockDim.x + threadIdx.x;
  if (i < G4) bs[i] = bi[i] + bh[i];
}

// xs[t][b][e] bf16 : t==0 -> features[b][e] ; t>=1 -> embed[captions[b][t-1]][e]
__global__ void build_xs_kernel(const float* __restrict__ features, const int* __restrict__ captions,
                                const float* __restrict__ embed, short* __restrict__ xs) {
  int i = blockIdx.x * blockDim.x + threadIdx.x;
  int stride = gridDim.x * blockDim.x;
  const int n = T_ * B_ * E_;
  for (; i < n; i += stride) {
    int t = i / (B_ * E_);
    int r = i - t * (B_ * E_);
    int b = r >> 9;       // /E_
    int e = r & 511;      // %E_
    float v;
    if (t == 0) v = features[b * E_ + e];
    else        v = embed[captions[b * T_ + (t - 1)] * E_ + e];
    xs[i] = f2bf(v);
  }
}

// ---------------- Gx GEMM: Gx[row=t*32+b][n] = xs @ W_ih^T + (b_ih+b_hh) ----------------
// M=2048, N=2048, K=512.  Block = 4 waves (2x2), 64x64 tile; each wave 32x32.

__global__ __launch_bounds__(256) void gemm_gx_kernel(const short* __restrict__ A,
                                                      const short* __restrict__ W,
                                                      const float* __restrict__ bias,
                                                      float* __restrict__ C) {
  const int lane = threadIdx.x & 63;
  const int wv   = threadIdx.x >> 6;
  const int m0 = blockIdx.y * 64 + (wv >> 1) * 32;
  const int n0 = blockIdx.x * 64 + (wv & 1) * 32;
  const int lr = lane & 15;
  const int ko = (lane >> 4) << 3;
  f32x4 acc[2][2] = {};
  const short* Ap = A + (m0 + lr) * 512 + ko;
  const short* Wp = W + (n0 + lr) * 512 + ko;
#pragma unroll
  for (int k = 0; k < 512; k += 32) {
    bf16x8 a0 = *(const bf16x8*)(Ap + k);
    bf16x8 a1 = *(const bf16x8*)(Ap + 16 * 512 + k);
    bf16x8 b0 = *(const bf16x8*)(Wp + k);
    bf16x8 b1 = *(const bf16x8*)(Wp + 16 * 512 + k);
    acc[0][0] = mfma16(a0, b0, acc[0][0]);
    acc[0][1] = mfma16(a0, b1, acc[0][1]);
    acc[1][0] = mfma16(a1, b0, acc[1][0]);
    acc[1][1] = mfma16(a1, b1, acc[1][1]);
  }
  const int cr = (lane >> 4) * 4, cc = lane & 15;
#pragma unroll
  for (int mi = 0; mi < 2; ++mi)
#pragma unroll
    for (int ni = 0; ni < 2; ++ni)
#pragma unroll
      for (int j = 0; j < 4; ++j) {
        int row = m0 + mi * 16 + cr + j;
        int col = n0 + ni * 16 + cc;
        C[row * G4 + col] = acc[mi][ni][j] + bias[col];
      }
}

// ---------------- persistent LSTM recurrence ----------------
// 32 blocks x 256 threads. Block b owns h columns [b*16, b*16+16).
// W_hh slice (4 gate-groups x 16 cols x 512 K, bf16) staged in LDS once.
// Per step: 4 waves each compute one gate group (32x16, K=512) via MFMA,
// add Gx, pointwise LSTM in fp32 (c kept in LDS), h written bf16 to global
// double-buffer + hs. Grid barrier: monotonic atomic counter + threadfence.

__global__ __launch_bounds__(256) void lstm_kernel(const short* __restrict__ Whh,
                                                   const float* __restrict__ Gx,
                                                   short* __restrict__ hbuf,
                                                   short* __restrict__ hs,
                                                   int* __restrict__ bar) {
  __shared__ short Wlds[64 * 512];    // 64 KB: [g*16+c][k]
  __shared__ float gl[4][32][16];     // gates staging
  __shared__ float cst[32][16];       // cell state fp32
  const int tid  = threadIdx.x;
  const int lane = tid & 63;
  const int wv   = tid >> 6;
  const int blk  = blockIdx.x;
  const int hc0  = blk * 16;

  // stage W_hh slice: Wlds[(g*16+c)*512+k] = Whh[(g*512+hc0+c)*512+k]
  for (int i = tid * 8; i < 64 * 512; i += 256 * 8) {
    int gc = i >> 9;
    int k  = i & 511;
    int g  = gc >> 4, c = gc & 15;
    *(bf16x8*)&Wlds[i] = *(const bf16x8*)&Whh[(g * 512 + hc0 + c) * 512 + k];
  }
  for (int e = tid; e < 512; e += 256) cst[e >> 4][e & 15] = 0.f;
  __syncthreads();

  const int lr = lane & 15;
  const int ko = (lane >> 4) << 3;
  const int cr = (lane >> 4) * 4, cc = lane & 15;

  for (int t = 0; t < T_; ++t) {
    if (t > 0) {
      // grid barrier #t: all 32 blocks wrote h[t-1]
      __syncthreads();
      if (tid == 0) {
        __hip_atomic_fetch_add(bar, 1, __ATOMIC_ACQ_REL, __HIP_MEMORY_SCOPE_AGENT);
        while (__hip_atomic_load(bar, __ATOMIC_ACQUIRE, __HIP_MEMORY_SCOPE_AGENT) < t * 32) {}
      }
      __syncthreads();
      __threadfence();  // acquire side: invalidate caches before reading h
    }
    f32x4 acc0 = {}, acc1 = {};
    if (t > 0) {
      const short* h  = hbuf + ((t - 1) & 1) * (B_ * H_);
      const short* Ap = h + lr * 512 + ko;
      const short* Wp = &Wlds[(wv * 16 + lr) * 512 + ko];
#pragma unroll
      for (int k = 0; k < 512; k += 32) {
        bf16x8 a0 = *(const bf16x8*)(Ap + k);
        bf16x8 a1 = *(const bf16x8*)(Ap + 16 * 512 + k);
        bf16x8 b  = *(const bf16x8*)(Wp + k);
        acc0 = mfma16(a0, b, acc0);
        acc1 = mfma16(a1, b, acc1);
      }
    }
    // gates = acc + Gx  -> LDS
    const float* Gt = Gx + t * B_ * G4 + wv * 512 + hc0;
#pragma unroll
    for (int j = 0; j < 4; ++j) {
      gl[wv][cr + j][cc]      = acc0[j] + Gt[(cr + j) * G4 + cc];
      gl[wv][16 + cr + j][cc] = acc1[j] + Gt[(16 + cr + j) * G4 + cc];
    }
    __syncthreads();
    // pointwise LSTM cell (fp32)
    for (int e = tid; e < 512; e += 256) {
      int r = e >> 4, c = e & 15;
      float ig = sigm(gl[0][r][c]);
      float fg = sigm(gl[1][r][c]);
      float gg = tanhf(gl[2][r][c]);
      float og = sigm(gl[3][r][c]);
      float cv = fg * cst[r][c] + ig * gg;
      float hv = og * tanhf(cv);
      cst[r][c] = cv;
      short hb = f2bf(hv);
      hbuf[(t & 1) * (B_ * H_) + r * 512 + hc0 + c] = hb;
      hs[(t * B_ + r) * 512 + hc0 + c] = hb;
    }
    __threadfence();   // release side: make h visible device-wide
    __syncthreads();   // protect gl/cst reuse next iteration
  }
}

// ---------------- FC GEMM: out[b][t][v] = hs @ fc_W^T + fc_b ----------------
// M=2048 (rows t*32+b), N=10000, K=512.

__global__ __launch_bounds__(256) void gemm_fc_kernel(const short* __restrict__ A,
                                                      const short* __restrict__ W,
                                                      const float* __restrict__ bias,
                                                      float* __restrict__ out) {
  const int lane = threadIdx.x & 63;
  const int wv   = threadIdx.x >> 6;
  const int m0 = blockIdx.y * 64 + (wv >> 1) * 32;
  const int n0 = blockIdx.x * 64 + (wv & 1) * 32;
  const int lr = lane & 15;
  const int ko = (lane >> 4) << 3;
  const int nr0 = n0 + lr, nr1 = n0 + 16 + lr;
  const bool v0 = nr0 < V_, v1 = nr1 < V_;
  f32x4 acc[2][2] = {};
  const short* Ap  = A + (m0 + lr) * 512 + ko;
  const short* Wp0 = W + nr0 * 512 + ko;
  const short* Wp1 = W + nr1 * 512 + ko;
  const bf16x8 zb = {};
#pragma unroll
  for (int k = 0; k < 512; k += 32) {
    bf16x8 a0 = *(const bf16x8*)(Ap + k);
    bf16x8 a1 = *(const bf16x8*)(Ap + 16 * 512 + k);
    bf16x8 b0 = v0 ? *(const bf16x8*)(Wp0 + k) : zb;
    bf16x8 b1 = v1 ? *(const bf16x8*)(Wp1 + k) : zb;
    acc[0][0] = mfma16(a0, b0, acc[0][0]);
    acc[0][1] = mfma16(a0, b1, acc[0][1]);
    acc[1][0] = mfma16(a1, b0, acc[1][0]);
    acc[1][1] = mfma16(a1, b1, acc[1][1]);
  }
  const int cr = (lane >> 4) * 4, cc = lane & 15;
#pragma unroll
  for (int mi = 0; mi < 2; ++mi)
#pragma unroll
    for (int ni = 0; ni < 2; ++ni)
#pragma unroll
      for (int j = 0; j < 4; ++j) {
        int row = m0 + mi * 16 + cr + j;
        int col = n0 + ni * 16 + cc;
        if (col < V_) {
          // row = t*32 + b  ->  out[b][t][col]
          out[(row & 31) * (T_ * V_) + (row >> 5) * V_ + col] = acc[mi][ni][j] + bias[col];
        }
      }
}

// ---------------- launch ----------------

extern "C" void kernel_launch(void* const* d_in, const int* in_sizes, int n_in,
                              void* d_out, int out_size, void* d_ws, size_t ws_size,
                              hipStream_t stream) {
  const float* features = (const float*)d_in[0];
  const int*   captions = (const int*)d_in[1];
  const float* embed    = (const float*)d_in[3];
  const float* W_ih     = (const float*)d_in[4];
  const float* W_hh     = (const float*)d_in[5];
  const float* b_ih     = (const float*)d_in[6];
  const float* b_hh     = (const float*)d_in[7];
  const float* fc_W     = (const float*)d_in[8];
  const float* fc_b     = (const float*)d_in[9];
  float* out = (float*)d_out;

  char* ws = (char*)d_ws;
  size_t off = 0;
  auto alloc = [&](size_t bytes) -> void* {
    off = (off + 255) & ~(size_t)255;
    void* p = ws + off;
    off += bytes;
    return p;
  };
  int*   bar    = (int*)  alloc(256);
  short* wih_bf = (short*)alloc((size_t)G4 * E_ * 2);
  short* whh_bf = (short*)alloc((size_t)G4 * H_ * 2);
  short* fcw_bf = (short*)alloc((size_t)V_ * H_ * 2);
  float* bsum   = (float*)alloc((size_t)G4 * 4);
  float* Gx     = (float*)alloc((size_t)T_ * B_ * G4 * 4);
  short* xs     = (short*)alloc((size_t)T_ * B_ * E_ * 2);
  short* hs     = (short*)alloc((size_t)T_ * B_ * H_ * 2);
  short* hbuf   = (short*)alloc((size_t)2 * B_ * H_ * 2);

  hipMemsetAsync(bar, 0, 256, stream);
  cast_bf16_kernel<<<1024, 256, 0, stream>>>(W_ih, wih_bf, G4 * E_);
  cast_bf16_kernel<<<1024, 256, 0, stream>>>(W_hh, whh_bf, G4 * H_);
  cast_bf16_kernel<<<2048, 256, 0, stream>>>(fc_W, fcw_bf, V_ * H_);
  bsum_kernel<<<8, 256, 0, stream>>>(b_ih, b_hh, bsum);
  build_xs_kernel<<<1024, 256, 0, stream>>>(features, captions, embed, xs);
  gemm_gx_kernel<<<dim3(32, 32), 256, 0, stream>>>(xs, wih_bf, bsum, Gx);
  lstm_kernel<<<32, 256, 0, stream>>>(whh_bf, Gx, hbuf, hs, bar);
  gemm_fc_kernel<<<dim3(157, 32), 256, 0, stream>>>(hs, fcw_bf, fc_b, out);
}

// Round 2
// 665.022 us; speedup vs baseline: 1.3465x; 1.3465x over previous
//
#include <hip/hip_runtime.h>
#include <hip/hip_bf16.h>

// Problem constants
#define B_ 32
#define T_ 64
#define E_ 512
#define H_ 512
#define V_ 10000
#define G4 2048   // 4*H

using bf16x8 = __attribute__((ext_vector_type(8))) short;  // 8 bf16 in 4 VGPRs
using f32x4  = __attribute__((ext_vector_type(4))) float;

__device__ inline f32x4 mfma16(bf16x8 a, bf16x8 b, f32x4 c) {
  return __builtin_amdgcn_mfma_f32_16x16x32_bf16(a, b, c, 0, 0, 0);
}

// fp32 -> bf16 round-to-nearest-even, stored as short
__device__ inline short f2bf(float x) {
  unsigned u = __builtin_bit_cast(unsigned, x);
  u = (u + 0x7fffu + ((u >> 16) & 1u)) >> 16;
  return (short)u;
}

__device__ inline float sigm(float x) { return 1.f / (1.f + expf(-x)); }

// Swizzled 16B LDS read: row stride 1024B, byte ^= (row&7)<<4 kills the
// 16-way bank conflict of the row-major [*][512] bf16 layout (guide G4).
__device__ inline bf16x8 lds_ld16B(const short* base, int row, int col) {
  int byte = (row << 10) + (col << 1);
  byte ^= (row & 7) << 4;
  return *(const bf16x8*)((const char*)base + byte);
}

// ---------------- prep kernels ----------------

__global__ void cast_bf16_kernel(const float* __restrict__ in, short* __restrict__ out, int n) {
  int i = blockIdx.x * blockDim.x + threadIdx.x;
  int stride = gridDim.x * blockDim.x;
  for (; i < n; i += stride) out[i] = f2bf(in[i]);
}

__global__ void bsum_kernel(const float* __restrict__ bi, const float* __restrict__ bh,
                            float* __restrict__ bs) {
  int i = blockIdx.x * blockDim.x + threadIdx.x;
  if (i < G4) bs[i] = bi[i] + bh[i];
}

// xs[t][b][e] bf16 : t==0 -> features[b][e] ; t>=1 -> embed[captions[b][t-1]][e]
__global__ void build_xs_kernel(const float* __restrict__ features, const int* __restrict__ captions,
                                const float* __restrict__ embed, short* __restrict__ xs) {
  int i = blockIdx.x * blockDim.x + threadIdx.x;
  int stride = gridDim.x * blockDim.x;
  const int n = T_ * B_ * E_;
  for (; i < n; i += stride) {
    int t = i / (B_ * E_);
    int r = i - t * (B_ * E_);
    int b = r >> 9;       // /E_
    int e = r & 511;      // %E_
    float v;
    if (t == 0) v = features[b * E_ + e];
    else        v = embed[captions[b * T_ + (t - 1)] * E_ + e];
    xs[i] = f2bf(v);
  }
}

// ---------------- Gx GEMM: Gx[row=t*32+b][n] = xs @ W_ih^T + (b_ih+b_hh) ----------------

__global__ __launch_bounds__(256) void gemm_gx_kernel(const short* __restrict__ A,
                                                      const short* __restrict__ W,
                                                      const float* __restrict__ bias,
                                                      float* __restrict__ C) {
  const int lane = threadIdx.x & 63;
  const int wv   = threadIdx.x >> 6;
  const int m0 = blockIdx.y * 64 + (wv >> 1) * 32;
  const int n0 = blockIdx.x * 64 + (wv & 1) * 32;
  const int lr = lane & 15;
  const int ko = (lane >> 4) << 3;
  f32x4 acc[2][2] = {};
  const short* Ap = A + (m0 + lr) * 512 + ko;
  const short* Wp = W + (n0 + lr) * 512 + ko;
#pragma unroll
  for (int k = 0; k < 512; k += 32) {
    bf16x8 a0 = *(const bf16x8*)(Ap + k);
    bf16x8 a1 = *(const bf16x8*)(Ap + 16 * 512 + k);
    bf16x8 b0 = *(const bf16x8*)(Wp + k);
    bf16x8 b1 = *(const bf16x8*)(Wp + 16 * 512 + k);
    acc[0][0] = mfma16(a0, b0, acc[0][0]);
    acc[0][1] = mfma16(a0, b1, acc[0][1]);
    acc[1][0] = mfma16(a1, b0, acc[1][0]);
    acc[1][1] = mfma16(a1, b1, acc[1][1]);
  }
  const int cr = (lane >> 4) * 4, cc = lane & 15;
#pragma unroll
  for (int mi = 0; mi < 2; ++mi)
#pragma unroll
    for (int ni = 0; ni < 2; ++ni)
#pragma unroll
      for (int j = 0; j < 4; ++j) {
        int row = m0 + mi * 16 + cr + j;
        int col = n0 + ni * 16 + cc;
        C[row * G4 + col] = acc[mi][ni][j] + bias[col];
      }
}

// ---------------- persistent LSTM recurrence ----------------
// 32 blocks x 256 threads. Block b owns h columns [b*16, b*16+16).
// h exchange: agent-scope RELAXED atomics (write-through / read-through the
// coherent point = Infinity Cache). NO __threadfence anywhere -> no L2
// writeback/invalidate per step. Barrier = monotonic relaxed atomic counter;
// __syncthreads' implicit vmcnt(0) drain orders the h stores before the bump.

__global__ __launch_bounds__(256) void lstm_kernel(const short* __restrict__ Whh,
                                                   const float* __restrict__ Gx,
                                                   unsigned* __restrict__ hbuf,  // 2 x 8192 u32 (packed 2xbf16)
                                                   unsigned* __restrict__ hs,    // T*B*H/2 u32
                                                   int* __restrict__ bar) {
  __shared__ short Wlds[64 * 512];    // 64 KB, swizzled
  __shared__ short hlds[32 * 512];    // 32 KB, swizzled
  __shared__ float gl[4][32][16];     // gates staging
  __shared__ float cst[32][16];       // cell state fp32
  const int tid  = threadIdx.x;
  const int lane = tid & 63;
  const int wv   = tid >> 6;
  const int blk  = blockIdx.x;
  const int hc0  = blk * 16;

  // stage W_hh slice (swizzled): logical row gc = g*16+c  <-  Whh row g*512+hc0+c
  for (int i = tid * 8; i < 64 * 512; i += 256 * 8) {
    int gc = i >> 9;
    int k  = i & 511;
    int g  = gc >> 4, c = gc & 15;
    bf16x8 v = *(const bf16x8*)&Whh[(g * 512 + hc0 + c) * 512 + k];
    int byte = (i * 2) ^ ((gc & 7) << 4);
    *(bf16x8*)((char*)Wlds + byte) = v;
  }
  {
    int e = tid * 2;
    cst[e >> 4][e & 15] = 0.f;
    cst[e >> 4][(e & 15) + 1] = 0.f;
  }
  __syncthreads();

  const int lr = lane & 15;
  const int ko = (lane >> 4) << 3;
  const int cr = (lane >> 4) * 4, cc = lane & 15;

  for (int t = 0; t < T_; ++t) {
    f32x4 acc0 = {}, acc1 = {};
    if (t > 0) {
      // ---- grid barrier #t: all 32 blocks stored h[t-1] (already at L3) ----
      __syncthreads();          // drains vmcnt(0): our h stores are at the coherent point
      if (tid == 0) {
        __hip_atomic_fetch_add(bar, 1, __ATOMIC_RELAXED, __HIP_MEMORY_SCOPE_AGENT);
        while (__hip_atomic_load(bar, __ATOMIC_RELAXED, __HIP_MEMORY_SCOPE_AGENT) < t * 32) {
          __builtin_amdgcn_s_sleep(2);
        }
      }
      __syncthreads();
      // ---- stage full h[t-1] (32KB) into LDS via coherent 8B loads ----
      const unsigned long long* hb =
          (const unsigned long long*)(hbuf + ((t - 1) & 1) * 8192);
      for (int j = tid; j < 4096; j += 256) {
        unsigned long long v =
            __hip_atomic_load(&hb[j], __ATOMIC_RELAXED, __HIP_MEMORY_SCOPE_AGENT);
        int row = j >> 7;                       // 4 shorts per u64, 256 shorts/row... (j*4)>>9
        int byte = (j * 8) ^ ((row & 7) << 4);  // same swizzle as reads
        *(unsigned long long*)((char*)hlds + byte) = v;
      }
      __syncthreads();
      // ---- h @ W_hh^T for this block's gate columns ----
#pragma unroll
      for (int k = 0; k < 512; k += 32) {
        bf16x8 a0 = lds_ld16B(hlds, lr, ko + k);
        bf16x8 a1 = lds_ld16B(hlds, lr + 16, ko + k);
        bf16x8 b  = lds_ld16B(Wlds, wv * 16 + lr, ko + k);
        acc0 = mfma16(a0, b, acc0);
        acc1 = mfma16(a1, b, acc1);
      }
    }
    // gates = acc + Gx  -> LDS
    const float* Gt = Gx + t * B_ * G4 + wv * 512 + hc0;
#pragma unroll
    for (int j = 0; j < 4; ++j) {
      gl[wv][cr + j][cc]      = acc0[j] + Gt[(cr + j) * G4 + cc];
      gl[wv][16 + cr + j][cc] = acc1[j] + Gt[(16 + cr + j) * G4 + cc];
    }
    __syncthreads();
    // pointwise LSTM cell (fp32), 2 elements per thread (adjacent cols)
    {
      int e0 = tid * 2;
      int r = e0 >> 4, c = e0 & 15;
      float2 gi = *(const float2*)&gl[0][r][c];
      float2 gf = *(const float2*)&gl[1][r][c];
      float2 gg = *(const float2*)&gl[2][r][c];
      float2 go = *(const float2*)&gl[3][r][c];
      float2 cp = *(const float2*)&cst[r][c];
      float c0 = sigm(gf.x) * cp.x + sigm(gi.x) * tanhf(gg.x);
      float c1 = sigm(gf.y) * cp.y + sigm(gi.y) * tanhf(gg.y);
      float h0 = sigm(go.x) * tanhf(c0);
      float h1 = sigm(go.y) * tanhf(c1);
      *(float2*)&cst[r][c] = make_float2(c0, c1);
      unsigned hp = (unsigned)(unsigned short)f2bf(h0) |
                    ((unsigned)(unsigned short)f2bf(h1) << 16);
      // coherent (agent-scope) store -> lands at Infinity Cache, no fence needed
      __hip_atomic_store(&hbuf[(t & 1) * 8192 + r * 256 + ((hc0 + c) >> 1)], hp,
                         __ATOMIC_RELAXED, __HIP_MEMORY_SCOPE_AGENT);
      hs[((t * B_ + r) * 512 + hc0 + c) >> 1] = hp;  // plain store: next kernel reads it
    }
    __syncthreads();  // protect gl/cst/hlds reuse next iteration
  }
}

// ---------------- FC GEMM: out[b][t][v] = hs @ fc_W^T + fc_b ----------------
// M=2048 (rows t*32+b), N=10000, K=512.

__global__ __launch_bounds__(256) void gemm_fc_kernel(const short* __restrict__ A,
                                                      const short* __restrict__ W,
                                                      const float* __restrict__ bias,
                                                      float* __restrict__ out) {
  const int lane = threadIdx.x & 63;
  const int wv   = threadIdx.x >> 6;
  const int m0 = blockIdx.y * 64 + (wv >> 1) * 32;
  const int n0 = blockIdx.x * 64 + (wv & 1) * 32;
  const int lr = lane & 15;
  const int ko = (lane >> 4) << 3;
  const int nr0 = n0 + lr, nr1 = n0 + 16 + lr;
  const bool v0 = nr0 < V_, v1 = nr1 < V_;
  f32x4 acc[2][2] = {};
  const short* Ap  = A + (m0 + lr) * 512 + ko;
  const short* Wp0 = W + nr0 * 512 + ko;
  const short* Wp1 = W + nr1 * 512 + ko;
  const bf16x8 zb = {};
#pragma unroll
  for (int k = 0; k < 512; k += 32) {
    bf16x8 a0 = *(const bf16x8*)(Ap + k);
    bf16x8 a1 = *(const bf16x8*)(Ap + 16 * 512 + k);
    bf16x8 b0 = v0 ? *(const bf16x8*)(Wp0 + k) : zb;
    bf16x8 b1 = v1 ? *(const bf16x8*)(Wp1 + k) : zb;
    acc[0][0] = mfma16(a0, b0, acc[0][0]);
    acc[0][1] = mfma16(a0, b1, acc[0][1]);
    acc[1][0] = mfma16(a1, b0, acc[1][0]);
    acc[1][1] = mfma16(a1, b1, acc[1][1]);
  }
  const int cr = (lane >> 4) * 4, cc = lane & 15;
#pragma unroll
  for (int mi = 0; mi < 2; ++mi)
#pragma unroll
    for (int ni = 0; ni < 2; ++ni)
#pragma unroll
      for (int j = 0; j < 4; ++j) {
        int row = m0 + mi * 16 + cr + j;
        int col = n0 + ni * 16 + cc;
        if (col < V_) {
          // row = t*32 + b  ->  out[b][t][col]
          out[(row & 31) * (T_ * V_) + (row >> 5) * V_ + col] = acc[mi][ni][j] + bias[col];
        }
      }
}

// ---------------- launch ----------------

extern "C" void kernel_launch(void* const* d_in, const int* in_sizes, int n_in,
                              void* d_out, int out_size, void* d_ws, size_t ws_size,
                              hipStream_t stream) {
  const float* features = (const float*)d_in[0];
  const int*   captions = (const int*)d_in[1];
  const float* embed    = (const float*)d_in[3];
  const float* W_ih     = (const float*)d_in[4];
  const float* W_hh     = (const float*)d_in[5];
  const float* b_ih     = (const float*)d_in[6];
  const float* b_hh     = (const float*)d_in[7];
  const float* fc_W     = (const float*)d_in[8];
  const float* fc_b     = (const float*)d_in[9];
  float* out = (float*)d_out;

  char* ws = (char*)d_ws;
  size_t off = 0;
  auto alloc = [&](size_t bytes) -> void* {
    off = (off + 255) & ~(size_t)255;
    void* p = ws + off;
    off += bytes;
    return p;
  };
  int*      bar    = (int*)     alloc(256);
  short*    wih_bf = (short*)   alloc((size_t)G4 * E_ * 2);
  short*    whh_bf = (short*)   alloc((size_t)G4 * H_ * 2);
  short*    fcw_bf = (short*)   alloc((size_t)V_ * H_ * 2);
  float*    bsum   = (float*)   alloc((size_t)G4 * 4);
  float*    Gx     = (float*)   alloc((size_t)T_ * B_ * G4 * 4);
  short*    xs     = (short*)   alloc((size_t)T_ * B_ * E_ * 2);
  unsigned* hs     = (unsigned*)alloc((size_t)T_ * B_ * H_ * 2);
  unsigned* hbuf   = (unsigned*)alloc((size_t)2 * 8192 * 4);

  hipMemsetAsync(bar, 0, 256, stream);
  cast_bf16_kernel<<<1024, 256, 0, stream>>>(W_ih, wih_bf, G4 * E_);
  cast_bf16_kernel<<<1024, 256, 0, stream>>>(W_hh, whh_bf, G4 * H_);
  cast_bf16_kernel<<<2048, 256, 0, stream>>>(fc_W, fcw_bf, V_ * H_);
  bsum_kernel<<<8, 256, 0, stream>>>(b_ih, b_hh, bsum);
  build_xs_kernel<<<1024, 256, 0, stream>>>(features, captions, embed, xs);
  gemm_gx_kernel<<<dim3(32, 32), 256, 0, stream>>>(xs, wih_bf, bsum, Gx);
  lstm_kernel<<<32, 256, 0, stream>>>(whh_bf, Gx, hbuf, (unsigned*)hs, bar);
  gemm_fc_kernel<<<dim3(157, 32), 256, 0, stream>>>((const short*)hs, fcw_bf, fc_b, out);
}

// Round 3
// 544.274 us; speedup vs baseline: 1.6452x; 1.2219x over previous
//
#include <hip/hip_runtime.h>
#include <hip/hip_bf16.h>

// Problem constants
#define B_ 32
#define T_ 64
#define E_ 512
#define H_ 512
#define V_ 10000
#define G4 2048   // 4*H

using bf16x8 = __attribute__((ext_vector_type(8))) short;  // 8 bf16 in 4 VGPRs
using f32x4  = __attribute__((ext_vector_type(4))) float;

__device__ inline f32x4 mfma16(bf16x8 a, bf16x8 b, f32x4 c) {
  return __builtin_amdgcn_mfma_f32_16x16x32_bf16(a, b, c, 0, 0, 0);
}

// fp32 -> bf16 round-to-nearest-even, stored as short
__device__ inline short f2bf(float x) {
  unsigned u = __builtin_bit_cast(unsigned, x);
  u = (u + 0x7fffu + ((u >> 16) & 1u)) >> 16;
  return (short)u;
}

__device__ inline float sigm(float x) { return 1.f / (1.f + expf(-x)); }

// Swizzled 16B LDS read: row stride 1024B, byte ^= (row&7)<<4 kills the
// 16-way bank conflict of the row-major [*][512] bf16 layout (guide G4).
__device__ inline bf16x8 lds_ld16B(const short* base, int row, int col) {
  int byte = (row << 10) + (col << 1);
  byte ^= (row & 7) << 4;
  return *(const bf16x8*)((const char*)base + byte);
}

// ---------------- prep kernels ----------------

__global__ void cast_bf16_kernel(const float* __restrict__ in, short* __restrict__ out, int n) {
  int i = blockIdx.x * blockDim.x + threadIdx.x;
  int stride = gridDim.x * blockDim.x;
  for (; i < n; i += stride) out[i] = f2bf(in[i]);
}

__global__ void bsum_kernel(const float* __restrict__ bi, const float* __restrict__ bh,
                            float* __restrict__ bs) {
  int i = blockIdx.x * blockDim.x + threadIdx.x;
  if (i < G4) bs[i] = bi[i] + bh[i];
}

// xs[t][b][e] bf16 : t==0 -> features[b][e] ; t>=1 -> embed[captions[b][t-1]][e]
__global__ void build_xs_kernel(const float* __restrict__ features, const int* __restrict__ captions,
                                const float* __restrict__ embed, short* __restrict__ xs) {
  int i = blockIdx.x * blockDim.x + threadIdx.x;
  int stride = gridDim.x * blockDim.x;
  const int n = T_ * B_ * E_;
  for (; i < n; i += stride) {
    int t = i / (B_ * E_);
    int r = i - t * (B_ * E_);
    int b = r >> 9;       // /E_
    int e = r & 511;      // %E_
    float v;
    if (t == 0) v = features[b * E_ + e];
    else        v = embed[captions[b * T_ + (t - 1)] * E_ + e];
    xs[i] = f2bf(v);
  }
}

// ---------------- Gx GEMM: Gx[row=t*32+b][n] = xs @ W_ih^T + (b_ih+b_hh) ----------------

__global__ __launch_bounds__(256) void gemm_gx_kernel(const short* __restrict__ A,
                                                      const short* __restrict__ W,
                                                      const float* __restrict__ bias,
                                                      float* __restrict__ C) {
  const int lane = threadIdx.x & 63;
  const int wv   = threadIdx.x >> 6;
  const int m0 = blockIdx.y * 64 + (wv >> 1) * 32;
  const int n0 = blockIdx.x * 64 + (wv & 1) * 32;
  const int lr = lane & 15;
  const int ko = (lane >> 4) << 3;
  f32x4 acc[2][2] = {};
  const short* Ap = A + (m0 + lr) * 512 + ko;
  const short* Wp = W + (n0 + lr) * 512 + ko;
#pragma unroll
  for (int k = 0; k < 512; k += 32) {
    bf16x8 a0 = *(const bf16x8*)(Ap + k);
    bf16x8 a1 = *(const bf16x8*)(Ap + 16 * 512 + k);
    bf16x8 b0 = *(const bf16x8*)(Wp + k);
    bf16x8 b1 = *(const bf16x8*)(Wp + 16 * 512 + k);
    acc[0][0] = mfma16(a0, b0, acc[0][0]);
    acc[0][1] = mfma16(a0, b1, acc[0][1]);
    acc[1][0] = mfma16(a1, b0, acc[1][0]);
    acc[1][1] = mfma16(a1, b1, acc[1][1]);
  }
  const int cr = (lane >> 4) * 4, cc = lane & 15;
#pragma unroll
  for (int mi = 0; mi < 2; ++mi)
#pragma unroll
    for (int ni = 0; ni < 2; ++ni)
#pragma unroll
      for (int j = 0; j < 4; ++j) {
        int row = m0 + mi * 16 + cr + j;
        int col = n0 + ni * 16 + cc;
        C[row * G4 + col] = acc[mi][ni][j] + bias[col];
      }
}

// ---------------- persistent LSTM recurrence ----------------
// 32 blocks x 256 threads. Block b owns h columns [b*16, b*16+16).
// Sync per step: flag-array barrier (one flag per block, separate lines,
// monotonic step value). h[t] is stored at a FRESH address each step
// (hs[t] itself) with agent-scope stores -> readers use plain cached 16B
// loads straight into MFMA (no staleness possible: address never seen
// before; stores are at the coherent point before the flag is raised).

__global__ __launch_bounds__(256) void lstm_kernel(const short* __restrict__ Whh,
                                                   const float* __restrict__ Gx,
                                                   short* __restrict__ hs,   // [T][B][H] bf16
                                                   int* __restrict__ flags) {
  __shared__ short Wlds[64 * 512];    // 64 KB, swizzled
  __shared__ float gl[4][32][18];     // gates staging (padded rows: conflict-free)
  __shared__ float cst[32][18];       // cell state fp32 (padded)
  const int tid  = threadIdx.x;
  const int lane = tid & 63;
  const int wv   = tid >> 6;
  const int blk  = blockIdx.x;
  const int hc0  = blk * 16;

  // stage W_hh slice (swizzled): logical row gc = g*16+c  <-  Whh row g*512+hc0+c
  for (int i = tid * 8; i < 64 * 512; i += 256 * 8) {
    int gc = i >> 9;
    int k  = i & 511;
    int g  = gc >> 4, c = gc & 15;
    bf16x8 v = *(const bf16x8*)&Whh[(g * 512 + hc0 + c) * 512 + k];
    int byte = (i * 2) ^ ((gc & 7) << 4);
    *(bf16x8*)((char*)Wlds + byte) = v;
  }
  const int pr = tid >> 3;            // pointwise row (batch) 0..31
  const int pc = (tid * 2) & 15;      // pointwise col pair base 0..14
  *(float2*)&cst[pr][pc] = make_float2(0.f, 0.f);
  __syncthreads();

  const int lr = lane & 15;
  const int ko = (lane >> 4) << 3;
  const int cr = (lane >> 4) * 4, cc = lane & 15;

  for (int t = 0; t < T_; ++t) {
    // prefetch this wave's Gx slice into registers (independent of h -> hides
    // under the flag poll)
    const float* Gt = Gx + t * B_ * G4 + wv * 512 + hc0;
    float gx0[4], gx1[4];
#pragma unroll
    for (int j = 0; j < 4; ++j) {
      gx0[j] = Gt[(cr + j) * G4 + cc];
      gx1[j] = Gt[(16 + cr + j) * G4 + cc];
    }
    f32x4 acc0 = {}, acc1 = {};
    if (t > 0) {
      // ---- wait until all 32 blocks raised flag >= t (h[t-1] at L3) ----
      for (;;) {
        int fl = __hip_atomic_load(&flags[(lane & 31) * 16], __ATOMIC_RELAXED,
                                   __HIP_MEMORY_SCOPE_AGENT);
        if (__all(fl >= t)) break;
      }
      asm volatile("" ::: "memory");  // no hoisting of h loads above the poll
      // ---- h[t-1] @ W_hh^T straight from global (fresh addresses) ----
      const short* Ap = hs + (t - 1) * (B_ * H_) + lr * 512 + ko;
#pragma unroll
      for (int k = 0; k < 512; k += 32) {
        bf16x8 a0 = *(const bf16x8*)(Ap + k);
        bf16x8 a1 = *(const bf16x8*)(Ap + 16 * 512 + k);
        bf16x8 b  = lds_ld16B(Wlds, wv * 16 + lr, ko + k);
        acc0 = mfma16(a0, b, acc0);
        acc1 = mfma16(a1, b, acc1);
      }
    }
    // gates = acc + Gx  -> LDS
#pragma unroll
    for (int j = 0; j < 4; ++j) {
      gl[wv][cr + j][cc]      = acc0[j] + gx0[j];
      gl[wv][16 + cr + j][cc] = acc1[j] + gx1[j];
    }
    __syncthreads();
    // pointwise LSTM cell (fp32), 2 adjacent elements per thread
    {
      float2 gi = *(const float2*)&gl[0][pr][pc];
      float2 gf = *(const float2*)&gl[1][pr][pc];
      float2 gg = *(const float2*)&gl[2][pr][pc];
      float2 go = *(const float2*)&gl[3][pr][pc];
      float2 cp = *(const float2*)&cst[pr][pc];
      float c0 = sigm(gf.x) * cp.x + sigm(gi.x) * tanhf(gg.x);
      float c1 = sigm(gf.y) * cp.y + sigm(gi.y) * tanhf(gg.y);
      float h0 = sigm(go.x) * tanhf(c0);
      float h1 = sigm(go.y) * tanhf(c1);
      *(float2*)&cst[pr][pc] = make_float2(c0, c1);
      unsigned hp = (unsigned)(unsigned short)f2bf(h0) |
                    ((unsigned)(unsigned short)f2bf(h1) << 16);
      int idx = (t * B_ + pr) * 512 + hc0 + pc;   // even
      // agent-scope store -> coherent point; visible to any XCD's fresh read
      __hip_atomic_store((unsigned*)hs + (idx >> 1), hp,
                         __ATOMIC_RELAXED, __HIP_MEMORY_SCOPE_AGENT);
    }
    __syncthreads();  // drains vmcnt: all h stores at L3; also protects gl/cst
    if (t < T_ - 1 && tid == 0) {
      __hip_atomic_store(&flags[blk * 16], t + 1, __ATOMIC_RELAXED,
                         __HIP_MEMORY_SCOPE_AGENT);
    }
  }
}

// ---------------- FC GEMM: out[b][t][v] = hs @ fc_W^T + fc_b ----------------
// M=2048 (rows t*32+b), N=10000, K=512.

__global__ __launch_bounds__(256) void gemm_fc_kernel(const short* __restrict__ A,
                                                      const short* __restrict__ W,
                                                      const float* __restrict__ bias,
                                                      float* __restrict__ out) {
  const int lane = threadIdx.x & 63;
  const int wv   = threadIdx.x >> 6;
  const int m0 = blockIdx.y * 64 + (wv >> 1) * 32;
  const int n0 = blockIdx.x * 64 + (wv & 1) * 32;
  const int lr = lane & 15;
  const int ko = (lane >> 4) << 3;
  const int nr0 = n0 + lr, nr1 = n0 + 16 + lr;
  const bool v0 = nr0 < V_, v1 = nr1 < V_;
  f32x4 acc[2][2] = {};
  const short* Ap  = A + (m0 + lr) * 512 + ko;
  const short* Wp0 = W + nr0 * 512 + ko;
  const short* Wp1 = W + nr1 * 512 + ko;
  const bf16x8 zb = {};
#pragma unroll
  for (int k = 0; k < 512; k += 32) {
    bf16x8 a0 = *(const bf16x8*)(Ap + k);
    bf16x8 a1 = *(const bf16x8*)(Ap + 16 * 512 + k);
    bf16x8 b0 = v0 ? *(const bf16x8*)(Wp0 + k) : zb;
    bf16x8 b1 = v1 ? *(const bf16x8*)(Wp1 + k) : zb;
    acc[0][0] = mfma16(a0, b0, acc[0][0]);
    acc[0][1] = mfma16(a0, b1, acc[0][1]);
    acc[1][0] = mfma16(a1, b0, acc[1][0]);
    acc[1][1] = mfma16(a1, b1, acc[1][1]);
  }
  const int cr = (lane >> 4) * 4, cc = lane & 15;
#pragma unroll
  for (int mi = 0; mi < 2; ++mi)
#pragma unroll
    for (int ni = 0; ni < 2; ++ni)
#pragma unroll
      for (int j = 0; j < 4; ++j) {
        int row = m0 + mi * 16 + cr + j;
        int col = n0 + ni * 16 + cc;
        if (col < V_) {
          // row = t*32 + b  ->  out[b][t][col]
          out[(row & 31) * (T_ * V_) + (row >> 5) * V_ + col] = acc[mi][ni][j] + bias[col];
        }
      }
}

// ---------------- launch ----------------

extern "C" void kernel_launch(void* const* d_in, const int* in_sizes, int n_in,
                              void* d_out, int out_size, void* d_ws, size_t ws_size,
                              hipStream_t stream) {
  const float* features = (const float*)d_in[0];
  const int*   captions = (const int*)d_in[1];
  const float* embed    = (const float*)d_in[3];
  const float* W_ih     = (const float*)d_in[4];
  const float* W_hh     = (const float*)d_in[5];
  const float* b_ih     = (const float*)d_in[6];
  const float* b_hh     = (const float*)d_in[7];
  const float* fc_W     = (const float*)d_in[8];
  const float* fc_b     = (const float*)d_in[9];
  float* out = (float*)d_out;

  char* ws = (char*)d_ws;
  size_t off = 0;
  auto alloc = [&](size_t bytes) -> void* {
    off = (off + 255) & ~(size_t)255;
    void* p = ws + off;
    off += bytes;
    return p;
  };
  int*      flags  = (int*)     alloc(4096);
  short*    wih_bf = (short*)   alloc((size_t)G4 * E_ * 2);
  short*    whh_bf = (short*)   alloc((size_t)G4 * H_ * 2);
  short*    fcw_bf = (short*)   alloc((size_t)V_ * H_ * 2);
  float*    bsum   = (float*)   alloc((size_t)G4 * 4);
  float*    Gx     = (float*)   alloc((size_t)T_ * B_ * G4 * 4);
  short*    xs     = (short*)   alloc((size_t)T_ * B_ * E_ * 2);
  short*    hs     = (short*)   alloc((size_t)T_ * B_ * H_ * 2);

  hipMemsetAsync(flags, 0, 4096, stream);
  cast_bf16_kernel<<<1024, 256, 0, stream>>>(W_ih, wih_bf, G4 * E_);
  cast_bf16_kernel<<<1024, 256, 0, stream>>>(W_hh, whh_bf, G4 * H_);
  cast_bf16_kernel<<<2048, 256, 0, stream>>>(fc_W, fcw_bf, V_ * H_);
  bsum_kernel<<<8, 256, 0, stream>>>(b_ih, b_hh, bsum);
  build_xs_kernel<<<1024, 256, 0, stream>>>(features, captions, embed, xs);
  gemm_gx_kernel<<<dim3(32, 32), 256, 0, stream>>>(xs, wih_bf, bsum, Gx);
  lstm_kernel<<<32, 256, 0, stream>>>(whh_bf, Gx, hs, flags);
  gemm_fc_kernel<<<dim3(157, 32), 256, 0, stream>>>(hs, fcw_bf, fc_b, out);
}